// Round 3
// baseline (436.511 us; speedup 1.0000x reference)
//
#include <hip/hip_runtime.h>
#include <stdint.h>

#define IN_F   4096
#define OUT_F  4096
#define M_ROWS 8192
#define RANK   8

typedef int v4i  __attribute__((ext_vector_type(4)));
typedef int v16i __attribute__((ext_vector_type(16)));

__device__ __forceinline__ int qclamp(float v, float inv) {
    float q = rintf(v * inv);                 // round-half-even = jnp.round
    q = fminf(fmaxf(q, -8.0f), 7.0f);
    return (int)q;
}

__device__ __forceinline__ uint32_t qpack4(float4 v, float inv) {
    uint32_t r =  (uint32_t)(qclamp(v.x, inv) & 0xFF)
               | ((uint32_t)(qclamp(v.y, inv) & 0xFF) << 8)
               | ((uint32_t)(qclamp(v.z, inv) & 0xFF) << 16)
               | ((uint32_t)(qclamp(v.w, inv) & 0xFF) << 24);
    return r;
}

// ---- kernel 1: merged-weight quant (unchanged from R2) ----
__global__ __launch_bounds__(256) void quant_w_k(
    const float* __restrict__ W, const float* __restrict__ lA,
    const float* __restrict__ lB, const float* __restrict__ sw,
    uint32_t* __restrict__ qw) {
    const int t = threadIdx.x;
    const int o = blockIdx.x;
    const float inv = 1.0f / sw[o];
    float br[RANK];
#pragma unroll
    for (int r = 0; r < RANK; ++r) br[r] = lB[o * RANK + r];
    const float4* Wo = (const float4*)(W + (size_t)o * IN_F);
    const float4* A4 = (const float4*)lA;
#pragma unroll
    for (int k = 0; k < 4; ++k) {
        int i = k * 256 + t;
        float4 w = Wo[i];
#pragma unroll
        for (int r = 0; r < RANK; ++r) {
            float4 a = A4[r * 1024 + i];
            w.x = fmaf(br[r], a.x, w.x);
            w.y = fmaf(br[r], a.y, w.y);
            w.z = fmaf(br[r], a.z, w.z);
            w.w = fmaf(br[r], a.w, w.w);
        }
        qw[(size_t)o * 1024 + i] = qpack4(w, inv);
    }
}

// ---- kernel 2: activation quant (unchanged from R2) ----
__global__ __launch_bounds__(256) void quant_x_k(
    const float* __restrict__ x, const float* __restrict__ ts,
    const int* __restrict__ step, uint32_t* __restrict__ qx) {
    const float inv = 1.0f / ts[step[0]];
    const int t = threadIdx.x;
    const size_t base = (size_t)blockIdx.x * 1024;
#pragma unroll
    for (int k = 0; k < 4; ++k) {
        size_t i = base + k * 256 + t;
        float4 v = ((const float4*)x)[i];
        qx[i] = qpack4(v, inv);
    }
}

// ---- kernel 3: i8 GEMM, 256x256 tile, 32x32x32 MFMA, m201-style phases ----
#define SKB   64                  // K bytes per subtile (one 32x32x32 needs 32; 2 kslices)
#define NSK   (IN_F / SKB)        // 64 subtiles
#define SLOTB (256 * SKB)         // 16 KiB per matrix per ring slot

__device__ __forceinline__ void gload16(const void* g, void* l) {
    __builtin_amdgcn_global_load_lds(
        (const __attribute__((address_space(1))) void*)g,
        (__attribute__((address_space(3))) void*)l,
        16, 0, 0);
}

__global__ __launch_bounds__(512, 2) void gemm_i8_k(
    const char* __restrict__ qx, const char* __restrict__ qw,
    const float* __restrict__ sw, const float* __restrict__ ts,
    const int* __restrict__ step, const float* __restrict__ bias,
    float* __restrict__ out) {

    __shared__ __attribute__((aligned(16))) char lsA[4][SLOTB];  // 64 KiB
    __shared__ __attribute__((aligned(16))) char lsB[4][SLOTB];  // 64 KiB

    const int t    = threadIdx.x;
    const int lane = t & 63;
    const int wave = t >> 6;          // 8 waves: 2M x 4N
    const int wm   = wave >> 2;       // rows wm*128
    const int wn   = wave & 3;        // cols wn*64

    // XCD swizzle: 512 blocks, 512 % 8 == 0 -> bijective
    int bid = blockIdx.x;
    int swz = (bid & 7) * 64 + (bid >> 3);
    const int tn = swz & 15;
    const int tm = swz >> 4;

    const char* gA = qx + (size_t)tm * 256 * IN_F;
    const char* gB = qw + (size_t)tn * 256 * IN_F;

    // stage half-subtile j of subtile S into ring slot: 2 gloads/thread
    auto stage_j = [&](int slot, int S, int j) {
        int i   = j * 512 + t;
        int row = i >> 2;
        int cg  = (i & 3) ^ ((row >> 1) & 3);     // inverse swizzle on SOURCE
        size_t goff = (size_t)row * IN_F + S * SKB + cg * 16;
        gload16(gA + goff, &lsA[slot][i * 16]);
        gload16(gB + goff, &lsB[slot][i * 16]);
    };
    auto rdA = [&](int slot, int mf, int ks) -> v4i {
        int r  = wm * 128 + mf * 32 + (lane & 31);
        int pc = (ks * 2 + (lane >> 5)) ^ ((r >> 1) & 3);
        return *(const v4i*)&lsA[slot][r * SKB + pc * 16];
    };
    auto rdB = [&](int slot, int nf, int ks) -> v4i {
        int r  = wn * 64 + nf * 32 + (lane & 31);
        int pc = (ks * 2 + (lane >> 5)) ^ ((r >> 1) & 3);
        return *(const v4i*)&lsB[slot][r * SKB + pc * 16];
    };

    v16i acc[4][2] = {};

    // prologue: stage subtiles 0,1,2 (12 loads/thread), ensure subtile 0
#pragma unroll
    for (int s = 0; s < 3; ++s) { stage_j(s, s, 0); stage_j(s, s, 1); }
    asm volatile("s_waitcnt vmcnt(8)" ::: "memory");
    __builtin_amdgcn_s_barrier();

    for (int T = 0; T < NSK; ++T) {
        const int sl = T & 3;

        // ---------- phase 0: mf 0-1 ----------
        v4i a0[2][2], b0[2][2];
#pragma unroll
        for (int mf = 0; mf < 2; ++mf)
#pragma unroll
            for (int ks = 0; ks < 2; ++ks) a0[mf][ks] = rdA(sl, mf, ks);
#pragma unroll
        for (int nf = 0; nf < 2; ++nf)
#pragma unroll
            for (int ks = 0; ks < 2; ++ks) b0[nf][ks] = rdB(sl, nf, ks);
        if (T + 3 < NSK) stage_j((T + 3) & 3, T + 3, 0);
        __builtin_amdgcn_s_barrier();
        asm volatile("s_waitcnt lgkmcnt(0)" ::: "memory");
        __builtin_amdgcn_sched_barrier(0);
        __builtin_amdgcn_s_setprio(1);
#pragma unroll
        for (int mf = 0; mf < 2; ++mf)
#pragma unroll
            for (int nf = 0; nf < 2; ++nf)
#pragma unroll
                for (int ks = 0; ks < 2; ++ks)
                    acc[mf][nf] = __builtin_amdgcn_mfma_i32_32x32x32_i8(
                        a0[mf][ks], b0[nf][ks], acc[mf][nf], 0, 0, 0);
        __builtin_amdgcn_s_setprio(0);
        __builtin_amdgcn_s_barrier();

        // ---------- phase 1: mf 2-3 (reuse b0) ----------
        v4i a1[2][2];
#pragma unroll
        for (int mf = 0; mf < 2; ++mf)
#pragma unroll
            for (int ks = 0; ks < 2; ++ks) a1[mf][ks] = rdA(sl, mf + 2, ks);
        if (T + 3 < NSK) stage_j((T + 3) & 3, T + 3, 1);
        // counted wait: ensure subtile T+1 landed before next phase-0 reads
        if (T < NSK - 3)       asm volatile("s_waitcnt vmcnt(8)" ::: "memory");
        else if (T == NSK - 3) asm volatile("s_waitcnt vmcnt(4)" ::: "memory");
        else if (T == NSK - 2) asm volatile("s_waitcnt vmcnt(0)" ::: "memory");
        __builtin_amdgcn_s_barrier();
        asm volatile("s_waitcnt lgkmcnt(0)" ::: "memory");
        __builtin_amdgcn_sched_barrier(0);
        __builtin_amdgcn_s_setprio(1);
#pragma unroll
        for (int mf = 0; mf < 2; ++mf)
#pragma unroll
            for (int nf = 0; nf < 2; ++nf)
#pragma unroll
                for (int ks = 0; ks < 2; ++ks)
                    acc[mf + 2][nf] = __builtin_amdgcn_mfma_i32_32x32x32_i8(
                        a1[mf][ks], b0[nf][ks], acc[mf + 2][nf], 0, 0, 0);
        __builtin_amdgcn_s_setprio(0);
        __builtin_amdgcn_s_barrier();
    }

    // epilogue: 32x32 D layout col=lane&31, row=(reg&3)+8*(reg>>2)+4*(lane>>5)
    const float s_x = ts[step[0]];
#pragma unroll
    for (int nf = 0; nf < 2; ++nf) {
        int col  = tn * 256 + wn * 64 + nf * 32 + (lane & 31);
        float sc = s_x * sw[col];
        float bv = bias[col];
#pragma unroll
        for (int mf = 0; mf < 4; ++mf) {
            int row_base = tm * 256 + wm * 128 + mf * 32 + (lane >> 5) * 4;
#pragma unroll
            for (int reg = 0; reg < 16; ++reg) {
                int row = row_base + (reg & 3) + 8 * (reg >> 2);
                out[(size_t)row * OUT_F + col] =
                    (float)acc[mf][nf][reg] * sc + bv;
            }
        }
    }
}

extern "C" void kernel_launch(void* const* d_in, const int* in_sizes, int n_in,
                              void* d_out, int out_size, void* d_ws, size_t ws_size,
                              hipStream_t stream) {
    const float* x    = (const float*)d_in[0];
    const float* W    = (const float*)d_in[1];
    const float* lA   = (const float*)d_in[2];
    const float* lB   = (const float*)d_in[3];
    const float* sw   = (const float*)d_in[4];
    const float* ts   = (const float*)d_in[5];
    const float* bias = (const float*)d_in[6];
    const int*   step = (const int*)d_in[7];
    float* out = (float*)d_out;

    char* qw = (char*)d_ws;                                   // 16 MiB
    char* qx = (char*)d_ws + (size_t)OUT_F * IN_F;            // 32 MiB

    quant_w_k<<<OUT_F, 256, 0, stream>>>(W, lA, lB, sw, (uint32_t*)qw);
    quant_x_k<<<M_ROWS * IN_F / 4096, 256, 0, stream>>>(x, ts, step, (uint32_t*)qx);

    gemm_i8_k<<<(M_ROWS / 256) * (OUT_F / 256), 512, 0, stream>>>(
        (const char*)qx, (const char*)qw, sw, ts, step, bias, out);
}

// Round 4
// 434.621 us; speedup vs baseline: 1.0043x; 1.0043x over previous
//
#include <hip/hip_runtime.h>
#include <stdint.h>

#define IN_F   4096
#define OUT_F  4096
#define M_ROWS 8192
#define RANK   8

typedef int v4i  __attribute__((ext_vector_type(4)));
typedef int v16i __attribute__((ext_vector_type(16)));

__device__ __forceinline__ int qclamp(float v, float inv) {
    float q = rintf(v * inv);                 // round-half-even = jnp.round
    q = fminf(fmaxf(q, -8.0f), 7.0f);
    return (int)q;
}

__device__ __forceinline__ uint32_t qpack4(float4 v, float inv) {
    uint32_t r =  (uint32_t)(qclamp(v.x, inv) & 0xFF)
               | ((uint32_t)(qclamp(v.y, inv) & 0xFF) << 8)
               | ((uint32_t)(qclamp(v.z, inv) & 0xFF) << 16)
               | ((uint32_t)(qclamp(v.w, inv) & 0xFF) << 24);
    return r;
}

// ---- kernel 1: merged-weight quant (unchanged) ----
__global__ __launch_bounds__(256) void quant_w_k(
    const float* __restrict__ W, const float* __restrict__ lA,
    const float* __restrict__ lB, const float* __restrict__ sw,
    uint32_t* __restrict__ qw) {
    const int t = threadIdx.x;
    const int o = blockIdx.x;
    const float inv = 1.0f / sw[o];
    float br[RANK];
#pragma unroll
    for (int r = 0; r < RANK; ++r) br[r] = lB[o * RANK + r];
    const float4* Wo = (const float4*)(W + (size_t)o * IN_F);
    const float4* A4 = (const float4*)lA;
#pragma unroll
    for (int k = 0; k < 4; ++k) {
        int i = k * 256 + t;
        float4 w = Wo[i];
#pragma unroll
        for (int r = 0; r < RANK; ++r) {
            float4 a = A4[r * 1024 + i];
            w.x = fmaf(br[r], a.x, w.x);
            w.y = fmaf(br[r], a.y, w.y);
            w.z = fmaf(br[r], a.z, w.z);
            w.w = fmaf(br[r], a.w, w.w);
        }
        qw[(size_t)o * 1024 + i] = qpack4(w, inv);
    }
}

// ---- kernel 2: activation quant (unchanged) ----
__global__ __launch_bounds__(256) void quant_x_k(
    const float* __restrict__ x, const float* __restrict__ ts,
    const int* __restrict__ step, uint32_t* __restrict__ qx) {
    const float inv = 1.0f / ts[step[0]];
    const int t = threadIdx.x;
    const size_t base = (size_t)blockIdx.x * 1024;
#pragma unroll
    for (int k = 0; k < 4; ++k) {
        size_t i = base + k * 256 + t;
        float4 v = ((const float4*)x)[i];
        qx[i] = qpack4(v, inv);
    }
}

// ---- kernel 3: i8 GEMM, 256x256 tile, R2 schedule + 32x32x32 MFMA ----
#define SKB   64                  // K bytes per subtile (two 32B k-slices)
#define NSK   (IN_F / SKB)        // 64 subtiles
#define SLOTB (256 * SKB)         // 16 KiB per matrix per ring slot

__device__ __forceinline__ void gload16(const void* g, void* l) {
    __builtin_amdgcn_global_load_lds(
        (const __attribute__((address_space(1))) void*)g,
        (__attribute__((address_space(3))) void*)l,
        16, 0, 0);
}

__global__ __launch_bounds__(512, 2) void gemm_i8_k(
    const char* __restrict__ qx, const char* __restrict__ qw,
    const float* __restrict__ sw, const float* __restrict__ ts,
    const int* __restrict__ step, const float* __restrict__ bias,
    float* __restrict__ out) {

    __shared__ __attribute__((aligned(16))) char lsA[4][SLOTB];  // 64 KiB
    __shared__ __attribute__((aligned(16))) char lsB[4][SLOTB];  // 64 KiB

    const int t    = threadIdx.x;
    const int lane = t & 63;
    const int wave = t >> 6;          // 8 waves: 2M x 4N
    const int wm   = wave >> 2;       // rows wm*128
    const int wn   = wave & 3;        // cols wn*64

    // XCD swizzle: 512 blocks, 512 % 8 == 0 -> bijective
    int bid = blockIdx.x;
    int swz = (bid & 7) * 64 + (bid >> 3);
    const int tn = swz & 15;
    const int tm = swz >> 4;

    const char* gA = qx + (size_t)tm * 256 * IN_F;
    const char* gB = qw + (size_t)tn * 256 * IN_F;

    // stage half-subtile j of subtile S: linear LDS dest, swizzled SOURCE
    auto stage_j = [&](int slot, int S, int j) {
        int i   = j * 512 + t;
        int row = i >> 2;
        int cg  = (i & 3) ^ ((row >> 1) & 3);
        size_t goff = (size_t)row * IN_F + S * SKB + cg * 16;
        gload16(gA + goff, &lsA[slot][i * 16]);
        gload16(gB + goff, &lsB[slot][i * 16]);
    };
    // 32x32x32 fragments: row = lane&31, 16B chunk = ks*2 + (lane>>5), swizzled
    auto rdA = [&](int slot, int mf, int ks) -> v4i {
        int r  = wm * 128 + mf * 32 + (lane & 31);
        int pc = (ks * 2 + (lane >> 5)) ^ ((r >> 1) & 3);
        return *(const v4i*)&lsA[slot][r * SKB + pc * 16];
    };
    auto rdB = [&](int slot, int nf, int ks) -> v4i {
        int r  = wn * 64 + nf * 32 + (lane & 31);
        int pc = (ks * 2 + (lane >> 5)) ^ ((r >> 1) & 3);
        return *(const v4i*)&lsB[slot][r * SKB + pc * 16];
    };

    v16i acc[4][2] = {};

    // prologue: stage subtiles 0,1,2
#pragma unroll
    for (int s = 0; s < 3; ++s) { stage_j(s, s, 0); stage_j(s, s, 1); }

    for (int T = 0; T < NSK; ++T) {
        const int sl = T & 3;
        // counted wait (R2 schedule): keep 8 loads (2 subtiles) in flight
        if (T < NSK - 2)       asm volatile("s_waitcnt vmcnt(8)" ::: "memory");
        else if (T == NSK - 2) asm volatile("s_waitcnt vmcnt(4)" ::: "memory");
        else                   asm volatile("s_waitcnt vmcnt(0)" ::: "memory");
        __builtin_amdgcn_s_barrier();   // tile T landed for all waves; each wave's
                                        // T-1 reads completed before its arrival

        v4i a[4][2], b[2][2];
#pragma unroll
        for (int mf = 0; mf < 4; ++mf)
#pragma unroll
            for (int ks = 0; ks < 2; ++ks) a[mf][ks] = rdA(sl, mf, ks);
#pragma unroll
        for (int nf = 0; nf < 2; ++nf)
#pragma unroll
            for (int ks = 0; ks < 2; ++ks) b[nf][ks] = rdB(sl, nf, ks);

        if (T + 3 < NSK) stage_j((T + 3) & 3, T + 3, 0);

        __builtin_amdgcn_s_setprio(1);
#pragma unroll
        for (int mf = 0; mf < 2; ++mf)
#pragma unroll
            for (int nf = 0; nf < 2; ++nf)
#pragma unroll
                for (int ks = 0; ks < 2; ++ks)
                    acc[mf][nf] = __builtin_amdgcn_mfma_i32_32x32x32_i8(
                        a[mf][ks], b[nf][ks], acc[mf][nf], 0, 0, 0);
        __builtin_amdgcn_s_setprio(0);

        if (T + 3 < NSK) stage_j((T + 3) & 3, T + 3, 1);

        __builtin_amdgcn_s_setprio(1);
#pragma unroll
        for (int mf = 2; mf < 4; ++mf)
#pragma unroll
            for (int nf = 0; nf < 2; ++nf)
#pragma unroll
                for (int ks = 0; ks < 2; ++ks)
                    acc[mf][nf] = __builtin_amdgcn_mfma_i32_32x32x32_i8(
                        a[mf][ks], b[nf][ks], acc[mf][nf], 0, 0, 0);
        __builtin_amdgcn_s_setprio(0);
    }

    // epilogue: 32x32 D layout col=lane&31, row=(reg&3)+8*(reg>>2)+4*(lane>>5)
    const float s_x = ts[step[0]];
#pragma unroll
    for (int nf = 0; nf < 2; ++nf) {
        int col  = tn * 256 + wn * 64 + nf * 32 + (lane & 31);
        float sc = s_x * sw[col];
        float bv = bias[col];
#pragma unroll
        for (int mf = 0; mf < 4; ++mf) {
            int row_base = tm * 256 + wm * 128 + mf * 32 + (lane >> 5) * 4;
#pragma unroll
            for (int reg = 0; reg < 16; ++reg) {
                int row = row_base + (reg & 3) + 8 * (reg >> 2);
                out[(size_t)row * OUT_F + col] =
                    (float)acc[mf][nf][reg] * sc + bv;
            }
        }
    }
}

extern "C" void kernel_launch(void* const* d_in, const int* in_sizes, int n_in,
                              void* d_out, int out_size, void* d_ws, size_t ws_size,
                              hipStream_t stream) {
    const float* x    = (const float*)d_in[0];
    const float* W    = (const float*)d_in[1];
    const float* lA   = (const float*)d_in[2];
    const float* lB   = (const float*)d_in[3];
    const float* sw   = (const float*)d_in[4];
    const float* ts   = (const float*)d_in[5];
    const float* bias = (const float*)d_in[6];
    const int*   step = (const int*)d_in[7];
    float* out = (float*)d_out;

    char* qw = (char*)d_ws;                                   // 16 MiB
    char* qx = (char*)d_ws + (size_t)OUT_F * IN_F;            // 32 MiB

    quant_w_k<<<OUT_F, 256, 0, stream>>>(W, lA, lB, sw, (uint32_t*)qw);
    quant_x_k<<<M_ROWS * IN_F / 4096, 256, 0, stream>>>(x, ts, step, (uint32_t*)qx);

    gemm_i8_k<<<(M_ROWS / 256) * (OUT_F / 256), 512, 0, stream>>>(
        (const char*)qx, (const char*)qw, sw, ts, step, bias, out);
}

// Round 8
// 419.627 us; speedup vs baseline: 1.0402x; 1.0357x over previous
//
#include <hip/hip_runtime.h>
#include <stdint.h>

#define IN_F   4096
#define OUT_F  4096
#define M_ROWS 8192
#define RANK   8

typedef int v4i __attribute__((ext_vector_type(4)));

__device__ __forceinline__ int qclamp(float v, float inv) {
    float q = rintf(v * inv);                 // round-half-even = jnp.round
    q = fminf(fmaxf(q, -8.0f), 7.0f);
    return (int)q;
}

__device__ __forceinline__ uint32_t qpack4(float4 v, float inv) {
    uint32_t r =  (uint32_t)(qclamp(v.x, inv) & 0xFF)
               | ((uint32_t)(qclamp(v.y, inv) & 0xFF) << 8)
               | ((uint32_t)(qclamp(v.z, inv) & 0xFF) << 16)
               | ((uint32_t)(qclamp(v.w, inv) & 0xFF) << 24);
    return r;
}

// ---- kernel 1: merged-weight quant (unchanged) ----
__global__ __launch_bounds__(256) void quant_w_k(
    const float* __restrict__ W, const float* __restrict__ lA,
    const float* __restrict__ lB, const float* __restrict__ sw,
    uint32_t* __restrict__ qw) {
    const int t = threadIdx.x;
    const int o = blockIdx.x;
    const float inv = 1.0f / sw[o];
    float br[RANK];
#pragma unroll
    for (int r = 0; r < RANK; ++r) br[r] = lB[o * RANK + r];
    const float4* Wo = (const float4*)(W + (size_t)o * IN_F);
    const float4* A4 = (const float4*)lA;
#pragma unroll
    for (int k = 0; k < 4; ++k) {
        int i = k * 256 + t;
        float4 w = Wo[i];
#pragma unroll
        for (int r = 0; r < RANK; ++r) {
            float4 a = A4[r * 1024 + i];
            w.x = fmaf(br[r], a.x, w.x);
            w.y = fmaf(br[r], a.y, w.y);
            w.z = fmaf(br[r], a.z, w.z);
            w.w = fmaf(br[r], a.w, w.w);
        }
        qw[(size_t)o * 1024 + i] = qpack4(w, inv);
    }
}

// ---- kernel 2: activation quant (unchanged) ----
__global__ __launch_bounds__(256) void quant_x_k(
    const float* __restrict__ x, const float* __restrict__ ts,
    const int* __restrict__ step, uint32_t* __restrict__ qx) {
    const float inv = 1.0f / ts[step[0]];
    const int t = threadIdx.x;
    const size_t base = (size_t)blockIdx.x * 1024;
#pragma unroll
    for (int k = 0; k < 4; ++k) {
        size_t i = base + k * 256 + t;
        float4 v = ((const float4*)x)[i];
        qx[i] = qpack4(v, inv);
    }
}

// ---- kernel 3: i8 GEMM, 256x256 tile, 16 waves of 64x64, R2 schedule ----
#define SKB   64                  // K bytes per subtile (one K=64 i8 MFMA)
#define NSK   (IN_F / SKB)        // 64 subtiles
#define SLOTB (256 * SKB)         // 16 KiB per matrix per ring slot

__device__ __forceinline__ void gload16(const void* g, void* l) {
    __builtin_amdgcn_global_load_lds(
        (const __attribute__((address_space(1))) void*)g,
        (__attribute__((address_space(3))) void*)l,
        16, 0, 0);
}

__global__ __launch_bounds__(1024, 4) void gemm_i8_k(
    const char* __restrict__ qx, const char* __restrict__ qw,
    const float* __restrict__ sw, const float* __restrict__ ts,
    const int* __restrict__ step, const float* __restrict__ bias,
    float* __restrict__ out) {

    __shared__ __attribute__((aligned(16))) char lsA[4][SLOTB];  // 64 KiB
    __shared__ __attribute__((aligned(16))) char lsB[4][SLOTB];  // 64 KiB

    const int t    = threadIdx.x;
    const int lane = t & 63;
    const int wave = t >> 6;          // 16 waves: 4M x 4N, each 64x64
    const int wm   = wave >> 2;
    const int wn   = wave & 3;

    // XCD swizzle: 512 blocks, 512 % 8 == 0 -> bijective
    int bid = blockIdx.x;
    int swz = (bid & 7) * 64 + (bid >> 3);
    const int tn = swz & 15;
    const int tm = swz >> 4;

    const char* gA = qx + (size_t)tm * 256 * IN_F;
    const char* gB = qw + (size_t)tn * 256 * IN_F;

    // stage subtile S into ring slot: 1 A-load + 1 B-load per thread.
    // Linear LDS dest (global_load_lds rule); XOR swizzle on the SOURCE.
    auto stage = [&](int slot, int S) {
        int row = t >> 2;
        int cg  = (t & 3) ^ ((row >> 1) & 3);
        size_t goff = (size_t)row * IN_F + S * SKB + cg * 16;
        gload16(gA + goff, &lsA[slot][t * 16]);
        gload16(gB + goff, &lsB[slot][t * 16]);
    };
    // proven-conflict-free read pattern: 4 quarters share 16 rows, chunk
    // = (lane>>4) ^ f(row), f = (r>>1)&3
    auto rdA = [&](int slot, int mi) -> v4i {
        int r  = wm * 64 + mi * 16 + (lane & 15);
        int pc = (lane >> 4) ^ ((r >> 1) & 3);
        return *(const v4i*)&lsA[slot][r * SKB + pc * 16];
    };
    auto rdB = [&](int slot, int ni) -> v4i {
        int r  = wn * 64 + ni * 16 + (lane & 15);
        int pc = (lane >> 4) ^ ((r >> 1) & 3);
        return *(const v4i*)&lsB[slot][r * SKB + pc * 16];
    };

    v4i acc[4][4] = {};

    // prologue: stage subtiles 0,1,2 (6 loads/thread)
#pragma unroll
    for (int s = 0; s < 3; ++s) stage(s, s);

    for (int T = 0; T < NSK; ++T) {
        const int sl = T & 3;
        // counted wait: tiles T+1, T+2 (4 loads) stay in flight
        if (T < NSK - 2)       asm volatile("s_waitcnt vmcnt(4)" ::: "memory");
        else if (T == NSK - 2) asm volatile("s_waitcnt vmcnt(2)" ::: "memory");
        else                   asm volatile("s_waitcnt vmcnt(0)" ::: "memory");
        __builtin_amdgcn_s_barrier();   // tile T landed; all waves' T-1 reads
                                        // retired before arrival -> T+3 staging safe

        v4i a[4], b[4];
#pragma unroll
        for (int mi = 0; mi < 4; ++mi) a[mi] = rdA(sl, mi);
#pragma unroll
        for (int ni = 0; ni < 4; ++ni) b[ni] = rdB(sl, ni);

        if (T + 3 < NSK) stage((T + 3) & 3, T + 3);

        __builtin_amdgcn_s_setprio(1);
#pragma unroll
        for (int mi = 0; mi < 4; ++mi)
#pragma unroll
            for (int ni = 0; ni < 4; ++ni)
                acc[mi][ni] = __builtin_amdgcn_mfma_i32_16x16x64_i8(
                    a[mi], b[ni], acc[mi][ni], 0, 0, 0);
        __builtin_amdgcn_s_setprio(0);
    }

    // epilogue: D layout col=lane&15, row=(lane>>4)*4+reg  [m89/m101]
    const float s_x = ts[step[0]];
#pragma unroll
    for (int ni = 0; ni < 4; ++ni) {
        int col  = tn * 256 + wn * 64 + ni * 16 + (lane & 15);
        float sc = s_x * sw[col];
        float bv = bias[col];
#pragma unroll
        for (int mi = 0; mi < 4; ++mi) {
            int row0 = tm * 256 + wm * 64 + mi * 16 + (lane >> 4) * 4;
#pragma unroll
            for (int r = 0; r < 4; ++r) {
                out[(size_t)(row0 + r) * OUT_F + col] =
                    (float)acc[mi][ni][r] * sc + bv;
            }
        }
    }
}

extern "C" void kernel_launch(void* const* d_in, const int* in_sizes, int n_in,
                              void* d_out, int out_size, void* d_ws, size_t ws_size,
                              hipStream_t stream) {
    const float* x    = (const float*)d_in[0];
    const float* W    = (const float*)d_in[1];
    const float* lA   = (const float*)d_in[2];
    const float* lB   = (const float*)d_in[3];
    const float* sw   = (const float*)d_in[4];
    const float* ts   = (const float*)d_in[5];
    const float* bias = (const float*)d_in[6];
    const int*   step = (const int*)d_in[7];
    float* out = (float*)d_out;

    char* qw = (char*)d_ws;                                   // 16 MiB
    char* qx = (char*)d_ws + (size_t)OUT_F * IN_F;            // 32 MiB

    quant_w_k<<<OUT_F, 256, 0, stream>>>(W, lA, lB, sw, (uint32_t*)qw);
    quant_x_k<<<M_ROWS * IN_F / 4096, 256, 0, stream>>>(x, ts, step, (uint32_t*)qx);

    gemm_i8_k<<<(M_ROWS / 256) * (OUT_F / 256), 1024, 0, stream>>>(
        (const char*)qx, (const char*)qw, sw, ts, step, bias, out);
}